// Round 1
// baseline (173.440 us; speedup 1.0000x reference)
//
#include <hip/hip_runtime.h>
#include <math.h>

#define B_    32
#define NV    32768
#define LA    64
#define DIM   128
#define OUTD  7
#define TOPK  10
#define CHUNK 2048
#define NCH   (NV / CHUNK)   // 16

// ---------------- K1: per-(b,l) sample threshold (upper bound on 10th-NN d2) ----
// grid (LA, B_), block 64 (one wave). Also zeroes the candidate counters.
__global__ void k1_threshold(const float* __restrict__ pos,
                             const float* __restrict__ lig,
                             float* __restrict__ T, unsigned int* __restrict__ cnt) {
  const int l = blockIdx.x, b = blockIdx.y;
  const int lane = threadIdx.x;
  const int bl = b * LA + l;
  if (lane == 0) cnt[bl] = 0u;
  const float lx = lig[bl * 3 + 0];
  const float ly = lig[bl * 3 + 1];
  const float lz = lig[bl * 3 + 2];
  float s[TOPK];
#pragma unroll
  for (int i = 0; i < TOPK; ++i) s[i] = INFINITY;
  const float* pb = pos + (size_t)b * NV * 3;
  // sample: every 16th vertex -> 2048 samples, 32 per lane
  for (int k = 0; k < 32; ++k) {
    int v = (lane + 64 * k) * 16;
    float dx = pb[v * 3 + 0] - lx;
    float dy = pb[v * 3 + 1] - ly;
    float dz = pb[v * 3 + 2] - lz;
    float d2 = fmaf(dx, dx, fmaf(dy, dy, dz * dz));
    if (d2 < s[TOPK - 1]) {
      s[TOPK - 1] = d2;
#pragma unroll
      for (int i = TOPK - 1; i >= 1; --i)
        if (s[i] < s[i - 1]) { float t = s[i]; s[i] = s[i - 1]; s[i - 1] = t; }
    }
  }
  // 10 rounds of wave-min with consume: T = 10th smallest sample d2
  float T10 = 0.f;
  for (int r = 0; r < TOPK; ++r) {
    float v = s[0];
#pragma unroll
    for (int o = 1; o < 64; o <<= 1) v = fminf(v, __shfl_xor(v, o, 64));
    T10 = v;
    if (s[0] == v) {  // consume (duplicate-consume only enlarges T: safe)
#pragma unroll
      for (int i = 0; i < TOPK - 1; ++i) s[i] = s[i + 1];
      s[TOPK - 1] = INFINITY;
    }
  }
  if (lane == 0) T[bl] = T10;
}

// ---------------- K2: filter pass -- append candidates with d2 <= T + slack ----
// grid (NCH, B_), block 256. Thread = (lg = tid>>4 in 0..15, vl = tid&15).
// Thread handles ligands {lg, lg+16, lg+32, lg+48}, vertices vl + 16k.
__global__ void k2_filter(const float* __restrict__ pos,
                          const float* __restrict__ lig,
                          const float* __restrict__ T,
                          unsigned int* __restrict__ cnt,
                          int* __restrict__ cand, int cap) {
  __shared__ float4 vp[CHUNK];  // x,y,z,pp  (32 KB)
  const int c = blockIdx.x, b = blockIdx.y;
  const int tid = threadIdx.x;
  const int base = c * CHUNK;
  const float* pb = pos + ((size_t)b * NV + base) * 3;
  // stage coords
  for (int j = tid; j < CHUNK * 3; j += 256) {
    int v = j / 3, comp = j - 3 * v;
    float val = pb[j];
    if (comp == 0) vp[v].x = val;
    else if (comp == 1) vp[v].y = val;
    else vp[v].z = val;
  }
  __syncthreads();
  // precompute pp per vertex (amortized over 64 ligands)
  for (int v = tid; v < CHUNK; v += 256) {
    float px = vp[v].x, py = vp[v].y, pz = vp[v].z;
    vp[v].w = fmaf(px, px, fmaf(py, py, pz * pz));
  }
  __syncthreads();
  const int lg = tid >> 4, vl = tid & 15;
  float Ax[4], Ay[4], Az[4], TH[4];
#pragma unroll
  for (int j = 0; j < 4; ++j) {
    int l = lg + 16 * j;
    float lx = lig[(b * LA + l) * 3 + 0];
    float ly = lig[(b * LA + l) * 3 + 1];
    float lz = lig[(b * LA + l) * 3 + 2];
    Ax[j] = -2.f * lx; Ay[j] = -2.f * ly; Az[j] = -2.f * lz;
    // d2 = pp + ll - 2 dot <= T + slack   <=>   pp - 2 dot <= T + slack - ll
    TH[j] = T[b * LA + l] + 0.01f - (lx * lx + ly * ly + lz * lz);
  }
  for (int k = 0; k < CHUNK / 16; ++k) {
    int v = vl + 16 * k;
    float4 p = vp[v];
#pragma unroll
    for (int j = 0; j < 4; ++j) {
      float t = fmaf(p.x, Ax[j], fmaf(p.y, Ay[j], fmaf(p.z, Az[j], p.w)));
      if (t <= TH[j]) {
        int l = lg + 16 * j;
        unsigned pidx = atomicAdd(&cnt[b * LA + l], 1u);
        if (pidx < (unsigned)cap) cand[(size_t)(b * LA + l) * cap + pidx] = base + v;
      }
    }
  }
}

// ---------------- K3: exact top-10 over candidate list --------------------------
// grid 2048 (=B_*LA), block 64 (one wave).
__global__ void k3_select(const float* __restrict__ pos,
                          const float* __restrict__ lig,
                          const unsigned int* __restrict__ cnt,
                          const int* __restrict__ cand, int cap,
                          int* __restrict__ sel) {
  const int bl = blockIdx.x;
  const int b = bl / LA;
  const int lane = threadIdx.x;
  const float lx = lig[bl * 3 + 0], ly = lig[bl * 3 + 1], lz = lig[bl * 3 + 2];
  int n = (int)min(cnt[bl], (unsigned)cap);
  unsigned long long s[TOPK];
#pragma unroll
  for (int i = 0; i < TOPK; ++i) s[i] = 0xFFFFFFFFFFFFFFFFull;
  const float* pb = pos + (size_t)b * NV * 3;
  for (int i = lane; i < n; i += 64) {
    int v = cand[(size_t)bl * cap + i];
    float dx = pb[v * 3 + 0] - lx;
    float dy = pb[v * 3 + 1] - ly;
    float dz = pb[v * 3 + 2] - lz;
    float d2 = fmaf(dx, dx, fmaf(dy, dy, dz * dz));
    unsigned long long key =
        ((unsigned long long)__float_as_uint(d2) << 32) | (unsigned int)v;
    if (key < s[TOPK - 1]) {
      s[TOPK - 1] = key;
#pragma unroll
      for (int i2 = TOPK - 1; i2 >= 1; --i2)
        if (s[i2] < s[i2 - 1]) {
          unsigned long long t = s[i2]; s[i2] = s[i2 - 1]; s[i2 - 1] = t;
        }
    }
  }
  // 10 rounds of wave-min consume; lane r stores round-r winner index.
  int prev = 0;
  for (int r = 0; r < TOPK; ++r) {
    unsigned long long v = s[0];
#pragma unroll
    for (int o = 1; o < 64; o <<= 1) {
      unsigned long long other = __shfl_xor(v, o, 64);
      v = (other < v) ? other : v;
    }
    if (s[0] == v) {
#pragma unroll
      for (int i = 0; i < TOPK - 1; ++i) s[i] = s[i + 1];
      s[TOPK - 1] = 0xFFFFFFFFFFFFFFFFull;
    }
    int idx = (int)(unsigned int)(v & 0xFFFFFFFFu);
    if ((v >> 32) == 0xFFFFFFFFull) idx = prev;  // pad guard (n<10: ~impossible)
    prev = idx;
    if (lane == r) sel[bl * TOPK + r] = idx;
  }
}

// ---------------- K4: dedup + masked mean + top_net MLP -------------------------
// grid B_, block 128 (= DIM).
__global__ void k4_gather_mlp(const float* __restrict__ x,
                              const int* __restrict__ sel,
                              const float* __restrict__ W1, const float* __restrict__ b1,
                              const float* __restrict__ gamma, const float* __restrict__ beta,
                              const float* __restrict__ rm, const float* __restrict__ rv,
                              const float* __restrict__ W2, const float* __restrict__ b2,
                              float* __restrict__ out) {
  __shared__ unsigned int maskW[NV / 32];  // 4 KB
  __shared__ int list[LA * TOPK];          // 2.56 KB
  __shared__ int cntS;
  __shared__ float embS[DIM];
  __shared__ float hS[DIM];
  const int b = blockIdx.x, tid = threadIdx.x;
  for (int w = tid; w < NV / 32; w += 128) maskW[w] = 0u;
  if (tid == 0) cntS = 0;
  __syncthreads();
  for (int i = tid; i < LA * TOPK; i += 128) {
    int v = sel[b * LA * TOPK + i];
    atomicOr(&maskW[v >> 5], 1u << (v & 31));
  }
  __syncthreads();
  for (int w = tid; w < NV / 32; w += 128) {
    unsigned int bits = maskW[w];
    int nb = __popc(bits);
    if (nb) {
      int p = atomicAdd(&cntS, nb);
      while (bits) {
        int bit = __ffs(bits) - 1;
        list[p++] = w * 32 + bit;
        bits &= bits - 1;
      }
    }
  }
  __syncthreads();
  const int cntU = cntS;
  // masked mean over unique vertices (f64 accumulation, 4-way ILP)
  const float* xb = x + (size_t)b * NV * DIM;
  const int d = tid;
  double a0 = 0, a1 = 0, a2 = 0, a3 = 0;
  int i = 0;
  for (; i + 3 < cntU; i += 4) {
    a0 += (double)xb[(size_t)list[i + 0] * DIM + d];
    a1 += (double)xb[(size_t)list[i + 1] * DIM + d];
    a2 += (double)xb[(size_t)list[i + 2] * DIM + d];
    a3 += (double)xb[(size_t)list[i + 3] * DIM + d];
  }
  for (; i < cntU; ++i) a0 += (double)xb[(size_t)list[i] * DIM + d];
  embS[d] = (float)(((a0 + a1) + (a2 + a3)) / (double)cntU);
  __syncthreads();
  // Linear1 + BatchNorm(eval) + SiLU
  float h = b1[d];
  for (int dd = 0; dd < DIM; ++dd) h = fmaf(embS[dd], W1[dd * DIM + d], h);
  h = (h - rm[d]) / sqrtf(rv[d] + 1e-5f) * gamma[d] + beta[d];
  h = h / (1.f + expf(-h));
  hS[d] = h;
  __syncthreads();
  if (tid < OUTD) {
    float o = b2[tid];
    for (int dd = 0; dd < DIM; ++dd) o = fmaf(hS[dd], W2[dd * OUTD + tid], o);
    out[b * OUTD + tid] = o;
  }
}

extern "C" void kernel_launch(void* const* d_in, const int* in_sizes, int n_in,
                              void* d_out, int out_size, void* d_ws, size_t ws_size,
                              hipStream_t stream) {
  const float* pos  = (const float*)d_in[0];
  const float* x    = (const float*)d_in[1];
  const float* lig  = (const float*)d_in[2];
  const float* W1   = (const float*)d_in[3];
  const float* b1   = (const float*)d_in[4];
  const float* gam  = (const float*)d_in[5];
  const float* bet  = (const float*)d_in[6];
  const float* rm   = (const float*)d_in[7];
  const float* rv   = (const float*)d_in[8];
  const float* W2   = (const float*)d_in[9];
  const float* b2   = (const float*)d_in[10];
  float* out = (float*)d_out;

  // workspace carve-up
  char* ws = (char*)d_ws;
  const int NBL = B_ * LA;  // 2048
  float* T          = (float*)(ws);                       // 8 KB
  unsigned int* cnt = (unsigned int*)(ws + NBL * 4);      // 8 KB
  int* sel          = (int*)(ws + NBL * 8);               // 80 KB
  int* cand         = (int*)(ws + NBL * 8 + NBL * TOPK * 4);
  size_t fixed = (size_t)NBL * 8 + (size_t)NBL * TOPK * 4;
  size_t avail = ws_size > fixed ? ws_size - fixed : 0;
  int cap = (int)((avail / ((size_t)NBL * 4)));
  if (cap > 1024) cap = 1024;
  if (cap < 16) cap = 16;  // degenerate ws; still deterministic

  k1_threshold<<<dim3(LA, B_), 64, 0, stream>>>(pos, lig, T, cnt);
  k2_filter<<<dim3(NCH, B_), 256, 0, stream>>>(pos, lig, T, cnt, cand, cap);
  k3_select<<<NBL, 64, 0, stream>>>(pos, lig, cnt, cand, cap, sel);
  k4_gather_mlp<<<B_, 128, 0, stream>>>(x, sel, W1, b1, gam, bet, rm, rv, W2, b2, out);
}

// Round 2
// 141.469 us; speedup vs baseline: 1.2260x; 1.2260x over previous
//
#include <hip/hip_runtime.h>
#include <math.h>

#define B_    32
#define NV    32768
#define LA    64
#define DIM   128
#define OUTD  7
#define TOPK  10
#define CHUNK 2048
#define NCH   (NV / CHUNK)   // 16
#define MAXU  (LA * TOPK)    // 640 max unique vertices per batch
#define NSEG  16             // gather segments per batch

// ---------------- K1: per-(b,l) sample threshold (upper bound on 10th-NN d2) ----
// grid (LA, B_), block 64 (one wave). Contiguous sample block (coalesced).
// Also zeroes the candidate counters.
__global__ void k1_threshold(const float* __restrict__ pos,
                             const float* __restrict__ lig,
                             float* __restrict__ T, unsigned int* __restrict__ cnt) {
  const int l = blockIdx.x, b = blockIdx.y;
  const int lane = threadIdx.x;
  const int bl = b * LA + l;
  if (lane == 0) cnt[bl] = 0u;
  const float lx = lig[bl * 3 + 0];
  const float ly = lig[bl * 3 + 1];
  const float lz = lig[bl * 3 + 2];
  float s[TOPK];
#pragma unroll
  for (int i = 0; i < TOPK; ++i) s[i] = INFINITY;
  const float* pb = pos + (size_t)b * NV * 3;
  // sample: first 2048 vertices (valid for any sample set; inputs are iid)
  for (int k = 0; k < 32; ++k) {
    int v = lane + 64 * k;
    float dx = pb[v * 3 + 0] - lx;
    float dy = pb[v * 3 + 1] - ly;
    float dz = pb[v * 3 + 2] - lz;
    float d2 = fmaf(dx, dx, fmaf(dy, dy, dz * dz));
    if (d2 < s[TOPK - 1]) {
      s[TOPK - 1] = d2;
#pragma unroll
      for (int i = TOPK - 1; i >= 1; --i)
        if (s[i] < s[i - 1]) { float t = s[i]; s[i] = s[i - 1]; s[i - 1] = t; }
    }
  }
  // 10 rounds of wave-min with consume: T = 10th smallest sample d2
  float T10 = 0.f;
  for (int r = 0; r < TOPK; ++r) {
    float v = s[0];
#pragma unroll
    for (int o = 1; o < 64; o <<= 1) v = fminf(v, __shfl_xor(v, o, 64));
    T10 = v;
    if (s[0] == v) {  // consume (duplicate-consume only enlarges T: safe)
#pragma unroll
      for (int i = 0; i < TOPK - 1; ++i) s[i] = s[i + 1];
      s[TOPK - 1] = INFINITY;
    }
  }
  if (lane == 0) T[bl] = T10;
}

// ---------------- K2: filter pass -- append candidates with d2 <= T + slack ----
// grid (NCH, B_), block 256. Thread = (lg = tid>>4 in 0..15, vl = tid&15).
__global__ void k2_filter(const float* __restrict__ pos,
                          const float* __restrict__ lig,
                          const float* __restrict__ T,
                          unsigned int* __restrict__ cnt,
                          int* __restrict__ cand, int cap) {
  __shared__ float4 vp[CHUNK];  // x,y,z,pp  (32 KB)
  const int c = blockIdx.x, b = blockIdx.y;
  const int tid = threadIdx.x;
  const int base = c * CHUNK;
  const float* pb = pos + ((size_t)b * NV + base) * 3;
  // stage coords (coalesced scalar)
  for (int j = tid; j < CHUNK * 3; j += 256) {
    int v = j / 3, comp = j - 3 * v;
    float val = pb[j];
    if (comp == 0) vp[v].x = val;
    else if (comp == 1) vp[v].y = val;
    else vp[v].z = val;
  }
  __syncthreads();
  for (int v = tid; v < CHUNK; v += 256) {
    float px = vp[v].x, py = vp[v].y, pz = vp[v].z;
    vp[v].w = fmaf(px, px, fmaf(py, py, pz * pz));
  }
  __syncthreads();
  const int lg = tid >> 4, vl = tid & 15;
  float Ax[4], Ay[4], Az[4], TH[4];
#pragma unroll
  for (int j = 0; j < 4; ++j) {
    int l = lg + 16 * j;
    float lx = lig[(b * LA + l) * 3 + 0];
    float ly = lig[(b * LA + l) * 3 + 1];
    float lz = lig[(b * LA + l) * 3 + 2];
    Ax[j] = -2.f * lx; Ay[j] = -2.f * ly; Az[j] = -2.f * lz;
    TH[j] = T[b * LA + l] + 0.01f - (lx * lx + ly * ly + lz * lz);
  }
  for (int k = 0; k < CHUNK / 16; ++k) {
    int v = vl + 16 * k;
    float4 p = vp[v];
#pragma unroll
    for (int j = 0; j < 4; ++j) {
      float t = fmaf(p.x, Ax[j], fmaf(p.y, Ay[j], fmaf(p.z, Az[j], p.w)));
      if (t <= TH[j]) {
        int l = lg + 16 * j;
        unsigned pidx = atomicAdd(&cnt[b * LA + l], 1u);
        if (pidx < (unsigned)cap) cand[(size_t)(b * LA + l) * cap + pidx] = base + v;
      }
    }
  }
}

// ---------------- K3: exact top-10 over candidate list --------------------------
// grid 2048 (=B_*LA), block 64 (one wave).
__global__ void k3_select(const float* __restrict__ pos,
                          const float* __restrict__ lig,
                          const unsigned int* __restrict__ cnt,
                          const int* __restrict__ cand, int cap,
                          int* __restrict__ sel) {
  const int bl = blockIdx.x;
  const int b = bl / LA;
  const int lane = threadIdx.x;
  const float lx = lig[bl * 3 + 0], ly = lig[bl * 3 + 1], lz = lig[bl * 3 + 2];
  int n = (int)min(cnt[bl], (unsigned)cap);
  unsigned long long s[TOPK];
#pragma unroll
  for (int i = 0; i < TOPK; ++i) s[i] = 0xFFFFFFFFFFFFFFFFull;
  const float* pb = pos + (size_t)b * NV * 3;
  for (int i = lane; i < n; i += 64) {
    int v = cand[(size_t)bl * cap + i];
    float dx = pb[v * 3 + 0] - lx;
    float dy = pb[v * 3 + 1] - ly;
    float dz = pb[v * 3 + 2] - lz;
    float d2 = fmaf(dx, dx, fmaf(dy, dy, dz * dz));
    unsigned long long key =
        ((unsigned long long)__float_as_uint(d2) << 32) | (unsigned int)v;
    if (key < s[TOPK - 1]) {
      s[TOPK - 1] = key;
#pragma unroll
      for (int i2 = TOPK - 1; i2 >= 1; --i2)
        if (s[i2] < s[i2 - 1]) {
          unsigned long long t = s[i2]; s[i2] = s[i2 - 1]; s[i2 - 1] = t;
        }
    }
  }
  int prev = 0;
  for (int r = 0; r < TOPK; ++r) {
    unsigned long long v = s[0];
#pragma unroll
    for (int o = 1; o < 64; o <<= 1) {
      unsigned long long other = __shfl_xor(v, o, 64);
      v = (other < v) ? other : v;
    }
    if (s[0] == v) {
#pragma unroll
      for (int i = 0; i < TOPK - 1; ++i) s[i] = s[i + 1];
      s[TOPK - 1] = 0xFFFFFFFFFFFFFFFFull;
    }
    int idx = (int)(unsigned int)(v & 0xFFFFFFFFu);
    if ((v >> 32) == 0xFFFFFFFFull) idx = prev;  // pad guard (n<10 impossible)
    prev = idx;
    if (lane == r) sel[bl * TOPK + r] = idx;
  }
}

// ---------------- K3b: per-batch dedup -> sorted unique list (deterministic) ----
// grid B_, block 256.
__global__ void k3b_dedup(const int* __restrict__ sel,
                          int* __restrict__ list, int* __restrict__ cntU) {
  __shared__ unsigned int maskW[NV / 32];  // 4 KB
  __shared__ int wordcnt[256];
  __shared__ int baseS[256];
  const int b = blockIdx.x, tid = threadIdx.x;
  for (int w = tid; w < NV / 32; w += 256) maskW[w] = 0u;
  __syncthreads();
  for (int i = tid; i < LA * TOPK; i += 256) {
    int v = sel[b * LA * TOPK + i];
    atomicOr(&maskW[v >> 5], 1u << (v & 31));
  }
  __syncthreads();
  int c = 0;
#pragma unroll
  for (int k = 0; k < 4; ++k) c += __popc(maskW[tid * 4 + k]);
  wordcnt[tid] = c;
  __syncthreads();
  if (tid == 0) {
    int s = 0;
    for (int t = 0; t < 256; ++t) { baseS[t] = s; s += wordcnt[t]; }
    cntU[b] = s;
  }
  __syncthreads();
  int p = baseS[tid];
#pragma unroll
  for (int k = 0; k < 4; ++k) {
    int w = tid * 4 + k;
    unsigned int bits = maskW[w];
    while (bits) {
      int bit = __ffs(bits) - 1;
      list[b * MAXU + p++] = w * 32 + bit;
      bits &= bits - 1;
    }
  }
}

// ---------------- K4a: parallel partial gather-sum (f64, deterministic) ---------
// grid (NSEG, B_), block 256. Thread = (rs = tid>>5 row slot, cg = tid&31 f4 col).
__global__ void k4a_gather(const float* __restrict__ x,
                           const int* __restrict__ list,
                           const int* __restrict__ cntU,
                           double* __restrict__ partial) {
  __shared__ double red[8][DIM];  // 8 KB
  const int seg = blockIdx.x, b = blockIdx.y, tid = threadIdx.x;
  const int n = cntU[b];
  const int r0 = (seg * n) / NSEG, r1 = ((seg + 1) * n) / NSEG;
  const int cg = tid & 31, rs = tid >> 5;
  double a0 = 0, a1 = 0, a2 = 0, a3 = 0;
  const float* xb = x + (size_t)b * NV * DIM;
  for (int i = r0 + rs; i < r1; i += 8) {
    int row = list[b * MAXU + i];
    float4 p = *(const float4*)(xb + (size_t)row * DIM + cg * 4);
    a0 += (double)p.x; a1 += (double)p.y; a2 += (double)p.z; a3 += (double)p.w;
  }
  red[rs][cg * 4 + 0] = a0;
  red[rs][cg * 4 + 1] = a1;
  red[rs][cg * 4 + 2] = a2;
  red[rs][cg * 4 + 3] = a3;
  __syncthreads();
  if (tid < DIM) {
    double s = 0;
#pragma unroll
    for (int r = 0; r < 8; ++r) s += red[r][tid];
    partial[((size_t)b * NSEG + seg) * DIM + tid] = s;
  }
}

// ---------------- K4b: reduce partials + top_net MLP ----------------------------
// grid B_, block 128 (= DIM).
__global__ void k4b_mlp(const double* __restrict__ partial,
                        const int* __restrict__ cntU,
                        const float* __restrict__ W1, const float* __restrict__ b1,
                        const float* __restrict__ gamma, const float* __restrict__ beta,
                        const float* __restrict__ rm, const float* __restrict__ rv,
                        const float* __restrict__ W2, const float* __restrict__ b2,
                        float* __restrict__ out) {
  __shared__ float embS[DIM];
  __shared__ float hS[DIM];
  const int b = blockIdx.x, d = threadIdx.x;
  double s = 0;
  for (int seg = 0; seg < NSEG; ++seg)
    s += partial[((size_t)b * NSEG + seg) * DIM + d];
  embS[d] = (float)(s / (double)cntU[b]);
  __syncthreads();
  float h = b1[d];
  for (int dd = 0; dd < DIM; ++dd) h = fmaf(embS[dd], W1[dd * DIM + d], h);
  h = (h - rm[d]) / sqrtf(rv[d] + 1e-5f) * gamma[d] + beta[d];
  h = h / (1.f + expf(-h));
  hS[d] = h;
  __syncthreads();
  if (d < OUTD) {
    float o = b2[d];
    for (int dd = 0; dd < DIM; ++dd) o = fmaf(hS[dd], W2[dd * OUTD + d], o);
    out[b * OUTD + d] = o;
  }
}

extern "C" void kernel_launch(void* const* d_in, const int* in_sizes, int n_in,
                              void* d_out, int out_size, void* d_ws, size_t ws_size,
                              hipStream_t stream) {
  const float* pos  = (const float*)d_in[0];
  const float* x    = (const float*)d_in[1];
  const float* lig  = (const float*)d_in[2];
  const float* W1   = (const float*)d_in[3];
  const float* b1   = (const float*)d_in[4];
  const float* gam  = (const float*)d_in[5];
  const float* bet  = (const float*)d_in[6];
  const float* rm   = (const float*)d_in[7];
  const float* rv   = (const float*)d_in[8];
  const float* W2   = (const float*)d_in[9];
  const float* b2   = (const float*)d_in[10];
  float* out = (float*)d_out;

  // workspace carve-up (all offsets 8-aligned where needed)
  char* ws = (char*)d_ws;
  const int NBL = B_ * LA;  // 2048
  float* T          = (float*)(ws);                                // 8 KB
  unsigned int* cnt = (unsigned int*)(ws + 8192);                  // 8 KB
  int* sel          = (int*)(ws + 16384);                          // 80 KB
  int* cntU         = (int*)(ws + 98304);                          // 256 B
  int* list         = (int*)(ws + 98560);                          // 80 KB
  double* partial   = (double*)(ws + 180480);                      // 512 KB
  int* cand         = (int*)(ws + 704768);
  size_t fixed = 704768;
  size_t avail = ws_size > fixed ? ws_size - fixed : 0;
  int cap = (int)(avail / ((size_t)NBL * 4));
  if (cap > 1024) cap = 1024;
  if (cap < 16) cap = 16;

  k1_threshold<<<dim3(LA, B_), 64, 0, stream>>>(pos, lig, T, cnt);
  k2_filter<<<dim3(NCH, B_), 256, 0, stream>>>(pos, lig, T, cnt, cand, cap);
  k3_select<<<NBL, 64, 0, stream>>>(pos, lig, cnt, cand, cap, sel);
  k3b_dedup<<<B_, 256, 0, stream>>>(sel, list, cntU);
  k4a_gather<<<dim3(NSEG, B_), 256, 0, stream>>>(x, list, cntU, partial);
  k4b_mlp<<<B_, 128, 0, stream>>>(partial, cntU, W1, b1, gam, bet, rm, rv, W2, b2, out);
}